// Round 5
// baseline (392.471 us; speedup 1.0000x reference)
//
#include <hip/hip_runtime.h>

#define B_   32
#define L_   200
#define DIM_ 36
#define ET_  128
#define NH_  64
#define SD_  9
#define NC_  2

// element offsets within d_out (float32)
#define O_TE   0
#define O_T1   147456
#define O_LG   294912
#define O_SXG  294976
#define O_SOUT 336448
#define O_QP   377920

__device__ __forceinline__ float sigm(float x) { return 1.f / (1.f + expf(-x)); }
// fast gate math: __expf + hw rcp (abs err ~1e-7, threshold is 4.6e-2)
__device__ __forceinline__ float fsigm(float x) {
  return __builtin_amdgcn_rcpf(1.f + __expf(-x));
}
__device__ __forceinline__ float ftanh(float x) {
  // 2*sigm(2x)-1; saturates correctly for |x| large (exp->inf -> rcp->0)
  return 2.f * __builtin_amdgcn_rcpf(1.f + __expf(-2.f * x)) - 1.f;
}

// ---------------------------------------------------------------------------
// K0: raw key time-embeddings e_k[b*l][128] (kw projection folded into qm2).
__global__ __launch_bounds__(256) void k_emb(
    const float* __restrict__ ts, const float* __restrict__ pw,
    const float* __restrict__ pb, const float* __restrict__ tlw,
    const float* __restrict__ tlb, float* __restrict__ ek) {
  float tw = tlw[0], tb = tlb[0];
  for (int idx = blockIdx.x * 256 + threadIdx.x; idx < B_ * L_ * ET_;
       idx += 256 * 256) {
    int row = idx >> 7, j = idx & 127;
    float t = ts[row];
    ek[idx] = (j == 0) ? t * tw + tb : __sinf(t * pw[j - 1] + pb[j - 1]);
  }
}

// ---------------------------------------------------------------------------
// K1: M[d][e] = sum_i qw[i][d] * kw[i][e]   (128x128, 16x16 tiles)
__global__ __launch_bounds__(256) void k_M(const float* __restrict__ qw,
                                           const float* __restrict__ kw,
                                           float* __restrict__ M) {
  __shared__ float qs[128][17];
  __shared__ float ks[128][17];
  int d0 = (blockIdx.x & 7) << 4, e0 = (blockIdx.x >> 3) << 4;
  for (int idx = threadIdx.x; idx < 128 * 16; idx += 256) {
    int i = idx >> 4, c = idx & 15;
    qs[i][c] = qw[i * 128 + d0 + c];
    ks[i][c] = kw[i * 128 + e0 + c];
  }
  __syncthreads();
  int dd = threadIdx.x & 15, ee = threadIdx.x >> 4;
  float a = 0.f;
  #pragma unroll 8
  for (int i = 0; i < 128; i++) a += qs[i][dd] * ks[i][ee];
  M[(d0 + dd) * 128 + e0 + ee] = a;
}

// ---------------------------------------------------------------------------
// K2: qm2[q][e] = (e_q[q]·M[:,e] + qb·kw[:,e]) / sqrt(128); qp passthrough.
__global__ __launch_bounds__(128) void k_qm2(
    const float* __restrict__ qp, const float* __restrict__ pw,
    const float* __restrict__ pb, const float* __restrict__ tlw,
    const float* __restrict__ tlb, const float* __restrict__ qb,
    const float* __restrict__ kw, const float* __restrict__ M,
    float* __restrict__ qm2, float* __restrict__ out) {
  __shared__ float eq[ET_];
  int q = blockIdx.x, e = threadIdx.x;
  float t = qp[q];
  eq[e] = (e == 0) ? t * tlw[0] + tlb[0] : sinf(t * pw[e - 1] + pb[e - 1]);
  __syncthreads();
  float a = 0.f;
  #pragma unroll 8
  for (int i = 0; i < ET_; i++) a += qb[i] * kw[i * ET_ + e];
  #pragma unroll 8
  for (int d = 0; d < ET_; d++) a += eq[d] * M[d * ET_ + e];
  qm2[q * ET_ + e] = a * 0.088388347648318447f;
  if (q == 0) out[O_QP + e] = qp[e];
}

// ---------------------------------------------------------------------------
// K3: xmean[b][d] = mean_l x[b,l,d] (fallback table).
__global__ __launch_bounds__(128) void k_xmean(const float* __restrict__ x,
                                               float* __restrict__ xmean) {
  int b = blockIdx.x;
  int d = threadIdx.x;
  if (d < 72) {
    float s = 0.f;
    #pragma unroll 8
    for (int l = 0; l < L_; l++) s += x[((size_t)b * L_ + l) * 72 + d];
    xmean[b * 72 + d] = s * (1.0f / L_);
  }
}

// ---------------------------------------------------------------------------
// K4 (fused attention): scores (qm2·e_k) -> rowmax -> e in LDS -> on-the-fly
// masked num/den sums -> divisions (+mean fallback) -> output projection.
__global__ __launch_bounds__(256) void k_attn(
    const float* __restrict__ qm, const float* __restrict__ ek,
    const float* __restrict__ x, const int* __restrict__ rm,
    const float* __restrict__ xmean, const float* __restrict__ ow,
    const float* __restrict__ ob, float* __restrict__ out) {
  __shared__ __align__(16) float qs[16][132];
  __shared__ __align__(16) float ks[16][132];
  __shared__ float sc[16][L_];
  __shared__ __align__(16) float xs[16][72];
  __shared__ float wsh[16][144];
  __shared__ float ofr[16][144];
  __shared__ __align__(16) float owsh[DIM_][72];
  __shared__ float rms[16];
  int b = blockIdx.x >> 3;
  int q0 = (blockIdx.x & 7) << 4;
  int tid = threadIdx.x;
  int qi = tid >> 4, li = tid & 15;

  const float4* qsrc = (const float4*)(qm + q0 * ET_);
  for (int idx = tid; idx < 16 * 32; idx += 256)
    ((float4*)qs[idx >> 5])[idx & 31] = qsrc[idx];
  const float4* owsrc = (const float4*)ow;
  for (int idx = tid; idx < DIM_ * 18; idx += 256)
    ((float4*)owsh[idx / 18])[idx % 18] = owsrc[idx];

  const float* kbp = ek + (size_t)b * L_ * ET_;
  for (int l0 = 0; l0 < L_; l0 += 16) {
    int nl = min(16, L_ - l0);
    __syncthreads();
    const float4* ksrc = (const float4*)(kbp + (size_t)l0 * ET_);
    for (int idx = tid; idx < nl * 32; idx += 256)
      ((float4*)ks[idx >> 5])[idx & 31] = ksrc[idx];
    __syncthreads();
    if (li < nl) {
      const float4* q4 = (const float4*)qs[qi];
      const float4* k4 = (const float4*)ks[li];
      float a0 = 0.f, a1 = 0.f, a2 = 0.f, a3 = 0.f;
      #pragma unroll 8
      for (int d4 = 0; d4 < 32; d4++) {
        float4 qv = q4[d4], kv = k4[d4];
        a0 += qv.x * kv.x; a1 += qv.y * kv.y;
        a2 += qv.z * kv.z; a3 += qv.w * kv.w;
      }
      sc[qi][l0 + li] = (a0 + a1) + (a2 + a3);
    }
  }
  __syncthreads();

  {
    float m = -1e30f;
    for (int l = li; l < L_; l += 16) m = fmaxf(m, sc[qi][l]);
    #pragma unroll
    for (int off = 8; off >= 1; off >>= 1) m = fmaxf(m, __shfl_xor(m, off));
    for (int l = li; l < L_; l += 16) sc[qi][l] = __expf(sc[qi][l] - m);
  }
  __syncthreads();

  float acc[9];
  #pragma unroll
  for (int r = 0; r < 9; r++) acc[r] = 0.f;
  const float* xb = x + (size_t)b * L_ * 72;
  const int* rmb = rm + b * L_;
  for (int l0 = 0; l0 < L_; l0 += 16) {
    int nl = min(16, L_ - l0);
    __syncthreads();
    const float4* xsrc = (const float4*)(xb + (size_t)l0 * 72);
    for (int idx = tid; idx < nl * 18; idx += 256)
      ((float4*)xs[idx / 18])[idx % 18] = xsrc[idx];
    if (tid < nl) rms[tid] = (float)rmb[l0 + tid];
    __syncthreads();
    for (int idx = tid; idx < nl * 144; idx += 256) {
      int l = idx / 144, c = idx % 144;
      int f = c % DIM_, seg = c / DIM_;
      float vv = xs[l][f], oo = xs[l][36 + f], rr = rms[l];
      float w;
      if (seg == 0)      w = oo * vv;
      else if (seg == 1) w = oo;
      else if (seg == 2) w = oo * vv * rr;
      else               w = oo * rr;
      wsh[l][c] = w;
    }
    __syncthreads();
    for (int l = 0; l < nl; l++) {
      float ev = sc[qi][l0 + l];
      #pragma unroll
      for (int r = 0; r < 9; r++) acc[r] += ev * wsh[l][li + r * 16];
    }
  }
  __syncthreads();
  #pragma unroll
  for (int r = 0; r < 9; r++) wsh[qi][li + r * 16] = acc[r];
  __syncthreads();

  const float* xm = xmean + b * 72;
  for (int idx = tid; idx < 16 * DIM_; idx += 256) {
    int qq = idx / DIM_, j = idx % DIM_;
    float numA = wsh[qq][j],      denA = wsh[qq][36 + j];
    float numB = wsh[qq][72 + j], denB = wsh[qq][108 + j];
    float al, ah, bl, bh;
    if (denA > 0.f) { al = numA / denA; ah = 1.f; }
    else            { al = xm[j];       ah = xm[36 + j]; }
    if (denB > 0.f) { bl = numB / denB; bh = 1.f; }
    else            { bl = xm[j];       bh = xm[36 + j]; }
    ofr[qq][j] = al;      ofr[qq][36 + j] = ah;
    ofr[qq][72 + j] = bl; ofr[qq][108 + j] = bh;
  }
  __syncthreads();

  for (int idx = tid; idx < 16 * 72; idx += 256) {
    int qq = idx / 72, t = idx % 72;
    int v = t / DIM_, i = t % DIM_;
    const float* o = &ofr[qq][v * 72];
    float a = ob[i];
    #pragma unroll 8
    for (int d = 0; d < 72; d++) a += o[d] * owsh[i][d];
    size_t off = ((size_t)b * ET_ + q0 + qq) * DIM_ + i;
    out[(v == 0 ? O_TE : O_T1) + off] = a;
  }
}

// ---------------------------------------------------------------------------
// K5: sx_g[b] = round(sigmoid(sx^T sx))   (36x36 over L)
__global__ __launch_bounds__(256) void k_sxg(const float* __restrict__ x,
                                             float* __restrict__ out) {
  __shared__ __align__(16) float sxs[L_][DIM_];
  int b = blockIdx.x;
  const float4* xsrc = (const float4*)(x + (size_t)b * L_ * 72);
  for (int idx = threadIdx.x; idx < L_ * 9; idx += 256) {
    int l = idx / 9, c = idx % 9;
    ((float4*)sxs[l])[c] = xsrc[l * 18 + c];
  }
  __syncthreads();
  for (int idx = threadIdx.x; idx < DIM_ * DIM_; idx += 256) {
    int d = idx / DIM_, e = idx % DIM_;
    float s = 0.f;
    #pragma unroll 8
    for (int l = 0; l < L_; l++) s += sxs[l][d] * sxs[l][e];
    out[O_SXG + (size_t)b * DIM_ * DIM_ + idx] = rintf(sigm(s));
  }
}

// ---------------------------------------------------------------------------
// K6: sout[b] = sigmoid(out_te^T out_te)   (36x36 over ET)
__global__ __launch_bounds__(256) void k_sout(const float* __restrict__ out_ro,
                                              float* __restrict__ out) {
  __shared__ __align__(16) float os[ET_][DIM_];
  int b = blockIdx.x;
  const float4* osrc = (const float4*)(out_ro + O_TE + (size_t)b * ET_ * DIM_);
  for (int idx = threadIdx.x; idx < ET_ * 9; idx += 256)
    ((float4*)os[idx / 9])[idx % 9] = osrc[idx];
  __syncthreads();
  for (int idx = threadIdx.x; idx < DIM_ * DIM_; idx += 256) {
    int d = idx / DIM_, e = idx % DIM_;
    float s = 0.f;
    #pragma unroll 8
    for (int q = 0; q < ET_; q++) s += os[q][d] * os[q][e];
    out[O_SOUT + (size_t)b * DIM_ * DIM_ + idx] = sigm(s);
  }
}

// ---------------------------------------------------------------------------
// K7: GRU. Phase 0: stage ote[b] -> LDS; wave-0 lanes prefetch whh (192 VGPR).
// Phase 1: 192 threads precompute gi for ALL 128 steps -> LDS (96KB).
// Phase 2: single-wave barrier-free scan: h in registers + LDS broadcast.
// __launch_bounds__(256,1): VGPR cap 512 -> no spills (R4: 84 VGPR => spilled).
__global__ __launch_bounds__(256, 1) void k_gru(
    const float* __restrict__ out_ro, const float* __restrict__ wih,
    const float* __restrict__ bih, const float* __restrict__ whh,
    const float* __restrict__ bhh, float* __restrict__ hfin) {
  __shared__ __align__(16) float ote_s[ET_][DIM_];   // 18 KB
  __shared__ float gis[ET_][3 * NH_];                // 96 KB
  __shared__ __align__(16) float hs[NH_];
  const float* ote = out_ro + O_TE;
  int b = blockIdx.x, t = threadIdx.x;

  // wave-0: prefetch whh rows for all 3 gates into VGPRs (issue early)
  float4 wr4[16], wz4[16], wn4[16];
  float bh_r = 0.f, bh_z = 0.f, bh_n = 0.f;
  if (t < NH_) {
    const float4* wr = (const float4*)(whh + (size_t)t * NH_);
    const float4* wz = (const float4*)(whh + (size_t)(NH_ + t) * NH_);
    const float4* wn = (const float4*)(whh + (size_t)(2 * NH_ + t) * NH_);
    #pragma unroll
    for (int c = 0; c < 16; c++) {
      wr4[c] = wr[c]; wz4[c] = wz[c]; wn4[c] = wn[c];
    }
    bh_r = bhh[t]; bh_z = bhh[NH_ + t]; bh_n = bhh[2 * NH_ + t];
    hs[t] = 0.f;
  }
  // stage ote[b] (coalesced float4)
  const float4* osrc = (const float4*)(ote + (size_t)b * ET_ * DIM_);
  for (int idx = t; idx < ET_ * DIM_ / 4; idx += 256)
    ((float4*)&ote_s[0][0])[idx] = osrc[idx];
  __syncthreads();

  // phase 1: gi[q][t] for t in [0,192) (wih row t held in VGPRs)
  if (t < 3 * NH_) {
    float wv[DIM_];
    const float* wrow = wih + (size_t)t * DIM_;
    #pragma unroll
    for (int d = 0; d < DIM_; d++) wv[d] = wrow[d];
    float bi = bih[t];
    for (int q = 0; q < ET_; q++) {
      const float4* xr = (const float4*)ote_s[q];
      float a = bi;
      #pragma unroll
      for (int c = 0; c < 9; c++) {
        float4 xv = xr[c];
        a += xv.x * wv[4 * c] + xv.y * wv[4 * c + 1] +
             xv.z * wv[4 * c + 2] + xv.w * wv[4 * c + 3];
      }
      gis[q][t] = a;
    }
  }
  __syncthreads();
  if (t >= NH_) return;

  // phase 2: barrier-free single-wave scan (intra-wave LDS ordering only)
  float h = 0.f;
  for (int q = 0; q < ET_; q++) {
    const float4* h4 = (const float4*)hs;
    float gr = bh_r, gz = bh_z, gn = bh_n;
    #pragma unroll
    for (int c = 0; c < 16; c++) {
      float4 hv = h4[c];
      gr += hv.x * wr4[c].x + hv.y * wr4[c].y + hv.z * wr4[c].z + hv.w * wr4[c].w;
      gz += hv.x * wz4[c].x + hv.y * wz4[c].y + hv.z * wz4[c].z + hv.w * wz4[c].w;
      gn += hv.x * wn4[c].x + hv.y * wn4[c].y + hv.z * wn4[c].z + hv.w * wn4[c].w;
    }
    float r = fsigm(gis[q][t] + gr);
    float z = fsigm(gis[q][NH_ + t] + gz);
    float n = ftanh(gis[q][2 * NH_ + t] + r * gn);
    h = (1.f - z) * n + z * h;
    hs[t] = h;  // publish for next step (same-wave lgkmcnt ordering)
  }
  hfin[b * NH_ + t] = h;
}

// ---------------------------------------------------------------------------
// K8: classifier head: st, concat, c1, batchnorm(batch), gelu, c2 -> logits
__global__ __launch_bounds__(256) void k_cls(
    const float* __restrict__ hfin, const float* __restrict__ si,
    const float* __restrict__ stw, const float* __restrict__ stb,
    const float* __restrict__ c1w, const float* __restrict__ c1b,
    const float* __restrict__ bng, const float* __restrict__ bnb,
    const float* __restrict__ c2w, const float* __restrict__ c2b,
    float* __restrict__ out) {
  __shared__ float cin[B_][72];
  __shared__ float z1[B_][72];
  __shared__ float zg[B_][72];
  int t = threadIdx.x;
  for (int idx = t; idx < B_ * 8; idx += 256) {
    int b = idx / 8, j = idx % 8;
    float acc = stb[j];
    #pragma unroll
    for (int d = 0; d < SD_; d++) acc += si[b * SD_ + d] * stw[j * SD_ + d];
    cin[b][NH_ + j] = acc;
  }
  for (int idx = t; idx < B_ * NH_; idx += 256)
    cin[idx / NH_][idx % NH_] = hfin[idx];
  __syncthreads();
  for (int idx = t; idx < B_ * 72; idx += 256) {
    int b = idx / 72, j = idx % 72;
    float acc = c1b[j];
    #pragma unroll 8
    for (int d = 0; d < 72; d++) acc += cin[b][d] * c1w[j * 72 + d];
    z1[b][j] = acc;
  }
  __syncthreads();
  if (t < 72) {
    float mu = 0.f;
    for (int b = 0; b < B_; b++) mu += z1[b][t];
    mu *= (1.f / B_);
    float vv = 0.f;
    for (int b = 0; b < B_; b++) { float d = z1[b][t] - mu; vv += d * d; }
    vv *= (1.f / B_);
    float inv = 1.f / sqrtf(vv + 1e-5f);
    float g = bng[t], bb = bnb[t];
    for (int b = 0; b < B_; b++) {
      float zn = (z1[b][t] - mu) * inv * g + bb;
      zg[b][t] = 0.5f * zn * (1.f + erff(zn * 0.70710678118654752f));
    }
  }
  __syncthreads();
  for (int idx = t; idx < B_ * NC_; idx += 256) {
    int b = idx / NC_, c = idx % NC_;
    float acc = c2b[c];
    #pragma unroll 8
    for (int d = 0; d < 72; d++) acc += zg[b][d] * c2w[c * 72 + d];
    out[O_LG + idx] = acc;
  }
}

// ---------------------------------------------------------------------------
extern "C" void kernel_launch(void* const* d_in, const int* in_sizes, int n_in,
                              void* d_out, int out_size, void* d_ws,
                              size_t ws_size, hipStream_t stream) {
  const float* x    = (const float*)d_in[0];
  const float* ts   = (const float*)d_in[1];
  const float* si   = (const float*)d_in[2];
  const float* qp   = (const float*)d_in[3];
  const float* pw   = (const float*)d_in[4];
  const float* pb   = (const float*)d_in[5];
  const float* tlw  = (const float*)d_in[6];
  const float* tlb  = (const float*)d_in[7];
  const float* qw   = (const float*)d_in[8];
  const float* qb   = (const float*)d_in[9];
  const float* kw   = (const float*)d_in[10];
  const float* ow   = (const float*)d_in[12];
  const float* ob   = (const float*)d_in[13];
  const float* wih  = (const float*)d_in[14];
  const float* whh  = (const float*)d_in[15];
  const float* bih  = (const float*)d_in[16];
  const float* bhh  = (const float*)d_in[17];
  const float* stw  = (const float*)d_in[18];
  const float* stb  = (const float*)d_in[19];
  const float* c1w  = (const float*)d_in[20];
  const float* c1b  = (const float*)d_in[21];
  const float* bng  = (const float*)d_in[22];
  const float* bnb  = (const float*)d_in[23];
  const float* c2w  = (const float*)d_in[24];
  const float* c2b  = (const float*)d_in[25];
  const int*   rm   = (const int*)d_in[26];

  float* out = (float*)d_out;

  // workspace: 856,320 floats = 3.43 MB
  float* W = (float*)d_ws;
  float* ws_ek    = W;            // 819200
  float* ws_qm2   = W + 819200;   // 16384
  float* ws_M     = W + 835584;   // 16384
  float* ws_xmean = W + 851968;   // 2304
  float* ws_hfin  = W + 854272;   // 2048

  hipLaunchKernelGGL(k_emb, dim3(256), dim3(256), 0, stream,
                     ts, pw, pb, tlw, tlb, ws_ek);
  hipLaunchKernelGGL(k_M, dim3(64), dim3(256), 0, stream, qw, kw, ws_M);
  hipLaunchKernelGGL(k_qm2, dim3(ET_), dim3(ET_), 0, stream,
                     qp, pw, pb, tlw, tlb, qb, kw, ws_M, ws_qm2, out);
  hipLaunchKernelGGL(k_xmean, dim3(B_), dim3(128), 0, stream, x, ws_xmean);
  hipLaunchKernelGGL(k_attn, dim3(B_ * 8), dim3(256), 0, stream,
                     ws_qm2, ws_ek, x, rm, ws_xmean, ow, ob, out);
  hipLaunchKernelGGL(k_sxg, dim3(B_), dim3(256), 0, stream, x, out);
  hipLaunchKernelGGL(k_sout, dim3(B_), dim3(256), 0, stream, out, out);
  hipLaunchKernelGGL(k_gru, dim3(B_), dim3(256), 0, stream,
                     out, wih, bih, whh, bhh, ws_hfin);
  hipLaunchKernelGGL(k_cls, dim3(1), dim3(256), 0, stream,
                     ws_hfin, si, stw, stb, c1w, c1b, bng, bnb, c2w, c2b,
                     out);
}

// Round 6
// 341.261 us; speedup vs baseline: 1.1501x; 1.1501x over previous
//
#include <hip/hip_runtime.h>

#define B_   32
#define L_   200
#define DIM_ 36
#define ET_  128
#define NH_  64
#define SD_  9
#define NC_  2

// element offsets within d_out (float32)
#define O_TE   0
#define O_T1   147456
#define O_LG   294912
#define O_SXG  294976
#define O_SOUT 336448
#define O_QP   377920

__device__ __forceinline__ float sigm(float x) { return 1.f / (1.f + expf(-x)); }
__device__ __forceinline__ float fsigm(float x) {
  return __builtin_amdgcn_rcpf(1.f + __expf(-x));
}
__device__ __forceinline__ float ftanh(float x) {
  return 2.f * __builtin_amdgcn_rcpf(1.f + __expf(-2.f * x)) - 1.f;
}

// ---------------------------------------------------------------------------
// K1: M[d][e] = sum_i qw[i][d] * kw[i][e]   (128x128, 16x16 tiles)
__global__ __launch_bounds__(256) void k_M(const float* __restrict__ qw,
                                           const float* __restrict__ kw,
                                           float* __restrict__ M) {
  __shared__ float qs[128][17];
  __shared__ float ks[128][17];
  int d0 = (blockIdx.x & 7) << 4, e0 = (blockIdx.x >> 3) << 4;
  for (int idx = threadIdx.x; idx < 128 * 16; idx += 256) {
    int i = idx >> 4, c = idx & 15;
    qs[i][c] = qw[i * 128 + d0 + c];
    ks[i][c] = kw[i * 128 + e0 + c];
  }
  __syncthreads();
  int dd = threadIdx.x & 15, ee = threadIdx.x >> 4;
  float a = 0.f;
  #pragma unroll 8
  for (int i = 0; i < 128; i++) a += qs[i][dd] * ks[i][ee];
  M[(d0 + dd) * 128 + e0 + ee] = a;
}

// ---------------------------------------------------------------------------
// K2: qm2[q][e] = (e_q[q]·M[:,e] + qb·kw[:,e]) / sqrt(128); qp passthrough.
__global__ __launch_bounds__(128) void k_qm2(
    const float* __restrict__ qp, const float* __restrict__ pw,
    const float* __restrict__ pb, const float* __restrict__ tlw,
    const float* __restrict__ tlb, const float* __restrict__ qb,
    const float* __restrict__ kw, const float* __restrict__ M,
    float* __restrict__ qm2, float* __restrict__ out) {
  __shared__ float eq[ET_];
  int q = blockIdx.x, e = threadIdx.x;
  float t = qp[q];
  eq[e] = (e == 0) ? t * tlw[0] + tlb[0] : sinf(t * pw[e - 1] + pb[e - 1]);
  __syncthreads();
  float a = 0.f;
  #pragma unroll 8
  for (int i = 0; i < ET_; i++) a += qb[i] * kw[i * ET_ + e];
  #pragma unroll 8
  for (int d = 0; d < ET_; d++) a += eq[d] * M[d * ET_ + e];
  qm2[q * ET_ + e] = a * 0.088388347648318447f;
  if (q == 0) out[O_QP + e] = qp[e];
}

// ---------------------------------------------------------------------------
// K3: xmean[b][d] = mean_l x[b,l,d] (fallback table).
__global__ __launch_bounds__(128) void k_xmean(const float* __restrict__ x,
                                               float* __restrict__ xmean) {
  int b = blockIdx.x;
  int d = threadIdx.x;
  if (d < 72) {
    float s = 0.f;
    #pragma unroll 8
    for (int l = 0; l < L_; l++) s += x[((size_t)b * L_ + l) * 72 + d];
    xmean[b * 72 + d] = s * (1.0f / L_);
  }
}

// ---------------------------------------------------------------------------
// K4 (fused attention): key embeddings computed ON THE FLY from ts/pw/pb
// (no ek workspace); scores -> rowmax -> e in LDS -> on-the-fly masked
// num/den sums -> divisions (+mean fallback) -> output projection.
__global__ __launch_bounds__(256) void k_attn(
    const float* __restrict__ qm, const float* __restrict__ ts,
    const float* __restrict__ pw, const float* __restrict__ pb,
    const float* __restrict__ tlw, const float* __restrict__ tlb,
    const float* __restrict__ x, const int* __restrict__ rm,
    const float* __restrict__ xmean, const float* __restrict__ ow,
    const float* __restrict__ ob, float* __restrict__ out) {
  __shared__ __align__(16) float qs[16][132];
  __shared__ float ks[16][132];
  __shared__ float sc[16][L_];
  __shared__ __align__(16) float xs[16][72];
  __shared__ float wsh[16][144];
  __shared__ float ofr[16][144];
  __shared__ __align__(16) float owsh[DIM_][72];
  __shared__ float rms[16];
  __shared__ float tsb[L_];
  __shared__ float cw[ET_], cb[ET_];
  int b = blockIdx.x >> 3;
  int q0 = (blockIdx.x & 7) << 4;
  int tid = threadIdx.x;
  int qi = tid >> 4, li = tid & 15;

  const float4* qsrc = (const float4*)(qm + q0 * ET_);
  for (int idx = tid; idx < 16 * 32; idx += 256)
    ((float4*)qs[idx >> 5])[idx & 31] = qsrc[idx];
  const float4* owsrc = (const float4*)ow;
  for (int idx = tid; idx < DIM_ * 18; idx += 256)
    ((float4*)owsh[idx / 18])[idx % 18] = owsrc[idx];
  for (int idx = tid; idx < ET_; idx += 256) {
    cw[idx] = (idx == 0) ? tlw[0] : pw[idx - 1];
    cb[idx] = (idx == 0) ? tlb[0] : pb[idx - 1];
  }
  for (int idx = tid; idx < L_; idx += 256) tsb[idx] = ts[b * L_ + idx];

  // --- scores: sc[q][l] = qm2[q]·e_k(ts[l]) ---
  for (int l0 = 0; l0 < L_; l0 += 16) {
    int nl = min(16, L_ - l0);
    __syncthreads();
    for (int idx = tid; idx < nl * ET_; idx += 256) {
      int l = idx >> 7, j = idx & 127;
      float tt = tsb[l0 + l];
      ks[l][j] = (j == 0) ? tt * cw[0] + cb[0] : __sinf(tt * cw[j] + cb[j]);
    }
    __syncthreads();
    if (li < nl) {
      const float4* q4 = (const float4*)qs[qi];
      const float* k1 = ks[li];
      float a0 = 0.f, a1 = 0.f, a2 = 0.f, a3 = 0.f;
      #pragma unroll 8
      for (int d4 = 0; d4 < 32; d4++) {
        float4 qv = q4[d4];
        a0 += qv.x * k1[4 * d4];     a1 += qv.y * k1[4 * d4 + 1];
        a2 += qv.z * k1[4 * d4 + 2]; a3 += qv.w * k1[4 * d4 + 3];
      }
      sc[qi][l0 + li] = (a0 + a1) + (a2 + a3);
    }
  }
  __syncthreads();

  {
    float m = -1e30f;
    for (int l = li; l < L_; l += 16) m = fmaxf(m, sc[qi][l]);
    #pragma unroll
    for (int off = 8; off >= 1; off >>= 1) m = fmaxf(m, __shfl_xor(m, off));
    for (int l = li; l < L_; l += 16) sc[qi][l] = __expf(sc[qi][l] - m);
  }
  __syncthreads();

  float acc[9];
  #pragma unroll
  for (int r = 0; r < 9; r++) acc[r] = 0.f;
  const float* xb = x + (size_t)b * L_ * 72;
  const int* rmb = rm + b * L_;
  for (int l0 = 0; l0 < L_; l0 += 16) {
    int nl = min(16, L_ - l0);
    __syncthreads();
    const float4* xsrc = (const float4*)(xb + (size_t)l0 * 72);
    for (int idx = tid; idx < nl * 18; idx += 256)
      ((float4*)xs[idx / 18])[idx % 18] = xsrc[idx];
    if (tid < nl) rms[tid] = (float)rmb[l0 + tid];
    __syncthreads();
    for (int idx = tid; idx < nl * 144; idx += 256) {
      int l = idx / 144, c = idx % 144;
      int f = c % DIM_, seg = c / DIM_;
      float vv = xs[l][f], oo = xs[l][36 + f], rr = rms[l];
      float w;
      if (seg == 0)      w = oo * vv;
      else if (seg == 1) w = oo;
      else if (seg == 2) w = oo * vv * rr;
      else               w = oo * rr;
      wsh[l][c] = w;
    }
    __syncthreads();
    for (int l = 0; l < nl; l++) {
      float ev = sc[qi][l0 + l];
      #pragma unroll
      for (int r = 0; r < 9; r++) acc[r] += ev * wsh[l][li + r * 16];
    }
  }
  __syncthreads();
  #pragma unroll
  for (int r = 0; r < 9; r++) wsh[qi][li + r * 16] = acc[r];
  __syncthreads();

  const float* xm = xmean + b * 72;
  for (int idx = tid; idx < 16 * DIM_; idx += 256) {
    int qq = idx / DIM_, j = idx % DIM_;
    float numA = wsh[qq][j],      denA = wsh[qq][36 + j];
    float numB = wsh[qq][72 + j], denB = wsh[qq][108 + j];
    float al, ah, bl, bh;
    if (denA > 0.f) { al = numA / denA; ah = 1.f; }
    else            { al = xm[j];       ah = xm[36 + j]; }
    if (denB > 0.f) { bl = numB / denB; bh = 1.f; }
    else            { bl = xm[j];       bh = xm[36 + j]; }
    ofr[qq][j] = al;      ofr[qq][36 + j] = ah;
    ofr[qq][72 + j] = bl; ofr[qq][108 + j] = bh;
  }
  __syncthreads();

  for (int idx = tid; idx < 16 * 72; idx += 256) {
    int qq = idx / 72, t = idx % 72;
    int v = t / DIM_, i = t % DIM_;
    const float* o = &ofr[qq][v * 72];
    float a = ob[i];
    #pragma unroll 8
    for (int d = 0; d < 72; d++) a += o[d] * owsh[i][d];
    size_t off = ((size_t)b * ET_ + q0 + qq) * DIM_ + i;
    out[(v == 0 ? O_TE : O_T1) + off] = a;
  }
}

// ---------------------------------------------------------------------------
// K5: sx_g[b] = round(sigmoid(sx^T sx))   (36x36 over L)
__global__ __launch_bounds__(256) void k_sxg(const float* __restrict__ x,
                                             float* __restrict__ out) {
  __shared__ __align__(16) float sxs[L_][DIM_];
  int b = blockIdx.x;
  const float4* xsrc = (const float4*)(x + (size_t)b * L_ * 72);
  for (int idx = threadIdx.x; idx < L_ * 9; idx += 256) {
    int l = idx / 9, c = idx % 9;
    ((float4*)sxs[l])[c] = xsrc[l * 18 + c];
  }
  __syncthreads();
  for (int idx = threadIdx.x; idx < DIM_ * DIM_; idx += 256) {
    int d = idx / DIM_, e = idx % DIM_;
    float s = 0.f;
    #pragma unroll 8
    for (int l = 0; l < L_; l++) s += sxs[l][d] * sxs[l][e];
    out[O_SXG + (size_t)b * DIM_ * DIM_ + idx] = rintf(sigm(s));
  }
}

// ---------------------------------------------------------------------------
// K6: sout[b] = sigmoid(out_te^T out_te)   (36x36 over ET)
__global__ __launch_bounds__(256) void k_sout(const float* __restrict__ out_ro,
                                              float* __restrict__ out) {
  __shared__ __align__(16) float os[ET_][DIM_];
  int b = blockIdx.x;
  const float4* osrc = (const float4*)(out_ro + O_TE + (size_t)b * ET_ * DIM_);
  for (int idx = threadIdx.x; idx < ET_ * 9; idx += 256)
    ((float4*)os[idx / 9])[idx % 9] = osrc[idx];
  __syncthreads();
  for (int idx = threadIdx.x; idx < DIM_ * DIM_; idx += 256) {
    int d = idx / DIM_, e = idx % DIM_;
    float s = 0.f;
    #pragma unroll 8
    for (int q = 0; q < ET_; q++) s += os[q][d] * os[q][e];
    out[O_SOUT + (size_t)b * DIM_ * DIM_ + idx] = sigm(s);
  }
}

// ---------------------------------------------------------------------------
// K7: GRU v3. 192 threads; thread t owns ONE whh row (16 float4 = 64 VGPR,
// far below the ~144 the allocator grants -> no spill, unlike R4/R5).
// Phase 0: stage ote[b]->LDS. Phase 1: gi for all 128 steps -> LDS.
// Phase 2: scan; per step all 192 threads GEMV their row (h broadcast from
// LDS), barrier, wave0 combines gates (gi prefetched pre-barrier), barrier.
__global__ __launch_bounds__(192, 1) void k_gru(
    const float* __restrict__ out_ro, const float* __restrict__ wih,
    const float* __restrict__ bih, const float* __restrict__ whh,
    const float* __restrict__ bhh, float* __restrict__ hfin) {
  __shared__ __align__(16) float ote_s[ET_][DIM_];  // 18 KB
  __shared__ float gis[ET_][3 * NH_];               // 96 KB
  __shared__ __align__(16) float hs[NH_];
  __shared__ float gh[3 * NH_];
  const float* ote = out_ro + O_TE;
  int b = blockIdx.x, t = threadIdx.x;

  // stage ote[b] (1152 float4, 6 per thread)
  const float4* osrc = (const float4*)(ote + (size_t)b * ET_ * DIM_);
  for (int idx = t; idx < ET_ * DIM_ / 4; idx += 192)
    ((float4*)&ote_s[0][0])[idx] = osrc[idx];
  if (t < NH_) hs[t] = 0.f;
  __syncthreads();

  // phase 1: gi[q][t] = bih[t] + ote[q]·wih[t]  (wih row in VGPRs)
  {
    float wv[DIM_];
    const float* wrow = wih + (size_t)t * DIM_;
    #pragma unroll
    for (int d = 0; d < DIM_; d++) wv[d] = wrow[d];
    float bi = bih[t];
    for (int q = 0; q < ET_; q++) {
      const float4* xr = (const float4*)ote_s[q];
      float a = bi;
      #pragma unroll
      for (int c = 0; c < 9; c++) {
        float4 xv = xr[c];
        a += xv.x * wv[4 * c] + xv.y * wv[4 * c + 1] +
             xv.z * wv[4 * c + 2] + xv.w * wv[4 * c + 3];
      }
      gis[q][t] = a;
    }
  }

  // load whh row t (issues overlap with other threads finishing phase 1)
  float4 w4[16];
  {
    const float4* wp = (const float4*)(whh + (size_t)t * NH_);
    #pragma unroll
    for (int c = 0; c < 16; c++) w4[c] = wp[c];
  }
  float bh = bhh[t];
  __syncthreads();

  // phase 2: scan
  float h = 0.f;
  for (int q = 0; q < ET_; q++) {
    float gi_r = 0.f, gi_z = 0.f, gi_n = 0.f;
    if (t < NH_) {  // prefetch gi before the barrier: latency hidden
      gi_r = gis[q][t];
      gi_z = gis[q][NH_ + t];
      gi_n = gis[q][2 * NH_ + t];
    }
    const float4* h4 = (const float4*)hs;
    float a0 = 0.f, a1 = 0.f, a2 = 0.f, a3 = 0.f;
    #pragma unroll
    for (int c = 0; c < 16; c++) {
      float4 hv = h4[c];
      a0 += hv.x * w4[c].x; a1 += hv.y * w4[c].y;
      a2 += hv.z * w4[c].z; a3 += hv.w * w4[c].w;
    }
    gh[t] = (a0 + a1) + (a2 + a3) + bh;
    __syncthreads();
    if (t < NH_) {
      float r = fsigm(gi_r + gh[t]);
      float z = fsigm(gi_z + gh[NH_ + t]);
      float n = ftanh(gi_n + r * gh[2 * NH_ + t]);
      h = (1.f - z) * n + z * h;
      hs[t] = h;
    }
    __syncthreads();
  }
  if (t < NH_) hfin[b * NH_ + t] = h;
}

// ---------------------------------------------------------------------------
// K8: classifier head: st, concat, c1, batchnorm(batch), gelu, c2 -> logits
__global__ __launch_bounds__(256) void k_cls(
    const float* __restrict__ hfin, const float* __restrict__ si,
    const float* __restrict__ stw, const float* __restrict__ stb,
    const float* __restrict__ c1w, const float* __restrict__ c1b,
    const float* __restrict__ bng, const float* __restrict__ bnb,
    const float* __restrict__ c2w, const float* __restrict__ c2b,
    float* __restrict__ out) {
  __shared__ float cin[B_][72];
  __shared__ float z1[B_][72];
  __shared__ float zg[B_][72];
  int t = threadIdx.x;
  for (int idx = t; idx < B_ * 8; idx += 256) {
    int b = idx / 8, j = idx % 8;
    float acc = stb[j];
    #pragma unroll
    for (int d = 0; d < SD_; d++) acc += si[b * SD_ + d] * stw[j * SD_ + d];
    cin[b][NH_ + j] = acc;
  }
  for (int idx = t; idx < B_ * NH_; idx += 256)
    cin[idx / NH_][idx % NH_] = hfin[idx];
  __syncthreads();
  for (int idx = t; idx < B_ * 72; idx += 256) {
    int b = idx / 72, j = idx % 72;
    float acc = c1b[j];
    #pragma unroll 8
    for (int d = 0; d < 72; d++) acc += cin[b][d] * c1w[j * 72 + d];
    z1[b][j] = acc;
  }
  __syncthreads();
  if (t < 72) {
    float mu = 0.f;
    for (int b = 0; b < B_; b++) mu += z1[b][t];
    mu *= (1.f / B_);
    float vv = 0.f;
    for (int b = 0; b < B_; b++) { float d = z1[b][t] - mu; vv += d * d; }
    vv *= (1.f / B_);
    float inv = 1.f / sqrtf(vv + 1e-5f);
    float g = bng[t], bb = bnb[t];
    for (int b = 0; b < B_; b++) {
      float zn = (z1[b][t] - mu) * inv * g + bb;
      zg[b][t] = 0.5f * zn * (1.f + erff(zn * 0.70710678118654752f));
    }
  }
  __syncthreads();
  for (int idx = t; idx < B_ * NC_; idx += 256) {
    int b = idx / NC_, c = idx % NC_;
    float acc = c2b[c];
    #pragma unroll 8
    for (int d = 0; d < 72; d++) acc += zg[b][d] * c2w[c * 72 + d];
    out[O_LG + idx] = acc;
  }
}

// ---------------------------------------------------------------------------
extern "C" void kernel_launch(void* const* d_in, const int* in_sizes, int n_in,
                              void* d_out, int out_size, void* d_ws,
                              size_t ws_size, hipStream_t stream) {
  const float* x    = (const float*)d_in[0];
  const float* ts   = (const float*)d_in[1];
  const float* si   = (const float*)d_in[2];
  const float* qp   = (const float*)d_in[3];
  const float* pw   = (const float*)d_in[4];
  const float* pb   = (const float*)d_in[5];
  const float* tlw  = (const float*)d_in[6];
  const float* tlb  = (const float*)d_in[7];
  const float* qw   = (const float*)d_in[8];
  const float* qb   = (const float*)d_in[9];
  const float* kw   = (const float*)d_in[10];
  const float* ow   = (const float*)d_in[12];
  const float* ob   = (const float*)d_in[13];
  const float* wih  = (const float*)d_in[14];
  const float* whh  = (const float*)d_in[15];
  const float* bih  = (const float*)d_in[16];
  const float* bhh  = (const float*)d_in[17];
  const float* stw  = (const float*)d_in[18];
  const float* stb  = (const float*)d_in[19];
  const float* c1w  = (const float*)d_in[20];
  const float* c1b  = (const float*)d_in[21];
  const float* bng  = (const float*)d_in[22];
  const float* bnb  = (const float*)d_in[23];
  const float* c2w  = (const float*)d_in[24];
  const float* c2b  = (const float*)d_in[25];
  const int*   rm   = (const int*)d_in[26];

  float* out = (float*)d_out;

  // workspace: 37,120 floats = 148 KB (ek eliminated)
  float* W = (float*)d_ws;
  float* ws_qm2   = W;            // 16384
  float* ws_M     = W + 16384;    // 16384
  float* ws_xmean = W + 32768;    // 2304
  float* ws_hfin  = W + 35072;    // 2048

  hipLaunchKernelGGL(k_M, dim3(64), dim3(256), 0, stream, qw, kw, ws_M);
  hipLaunchKernelGGL(k_qm2, dim3(ET_), dim3(ET_), 0, stream,
                     qp, pw, pb, tlw, tlb, qb, kw, ws_M, ws_qm2, out);
  hipLaunchKernelGGL(k_xmean, dim3(B_), dim3(128), 0, stream, x, ws_xmean);
  hipLaunchKernelGGL(k_attn, dim3(B_ * 8), dim3(256), 0, stream,
                     ws_qm2, ts, pw, pb, tlw, tlb, x, rm, ws_xmean, ow, ob,
                     out);
  hipLaunchKernelGGL(k_sxg, dim3(B_), dim3(256), 0, stream, x, out);
  hipLaunchKernelGGL(k_sout, dim3(B_), dim3(256), 0, stream, out, out);
  hipLaunchKernelGGL(k_gru, dim3(B_), dim3(192), 0, stream,
                     out, wih, bih, whh, bhh, ws_hfin);
  hipLaunchKernelGGL(k_cls, dim3(1), dim3(256), 0, stream,
                     ws_hfin, si, stw, stb, c1w, c1b, bng, bnb, c2w, c2b,
                     out);
}